// Round 1
// baseline (3260.939 us; speedup 1.0000x reference)
//
#include <hip/hip_runtime.h>

// ---------------------------------------------------------------------------
// Gemma3 prefill forward, MI355X (gfx950).
// Shapes: L=12 D=1152 NH=4 NG=1 HD=256 F=6912 V=32768 T=128 C=1920 S=2048
// This revision: all weight GEMMs stage B through LDS (coalesced float4
// global loads, depth-3 register prefetch, bf16 k-sliced XOR-swizzled LDS
// layout, one ds_read_b128 per B fragment) instead of 8 strided scalar
// loads per fragment. Flash attention: early-exit fully-masked local chunks.
// ---------------------------------------------------------------------------

using f4  = __attribute__((ext_vector_type(4))) float;
using s8v = __attribute__((ext_vector_type(8))) short;

__device__ inline short f2bf(float f) {
  union { float f; unsigned u; } v; v.f = f;
  unsigned r = v.u + 0x7fffu + ((v.u >> 16) & 1u);
  return (short)(r >> 16);
}
__device__ inline float bf2f(short s) {
  union { unsigned u; float f; } v; v.u = ((unsigned)(unsigned short)s) << 16;
  return v.f;
}
// n-slot swizzle: spreads banks for both 2B staging writes and b128 reads.
__device__ inline int bslot(int n) {
  return (n & ~7) | ((n & 7) ^ ((n >> 3) & 7));
}

constexpr int   Dm  = 1152;
constexpr int   HD  = 256;
constexpr int   Fm  = 6912;
constexpr int   Vv  = 32768;
constexpr int   Tm  = 128;
constexpr int   Cm  = 1920;
constexpr float LOG2E = 1.4426950408889634f;
// 2*scale/(CAP*ln2), scale=1/16, CAP=50
constexpr float K_TANH = 0.003606737602222409f;

// ---------------------------------------------------------------------------
// Generic GEMM: out[ns][128][N] (bf16 or fp32) = A(128xK bf16) @ B(KxN fp32)
// BN=64 fixed. 4 waves, wave w owns rows [w*32, w*32+32), all 64 cols.
// B staged via LDS: k-sliced swizzled bf16 layout, depth-3 reg prefetch.
//   lds elem addr(k,n) = (k>>3)*512 + bslot(n)*8 + (k&7)
// ---------------------------------------------------------------------------
template<int NSPLIT, bool OUT_BF16>
__global__ __launch_bounds__(256, 2) void gemm_bf16(
    const short* __restrict__ A, const float* __restrict__ B,
    void* __restrict__ outv, int K, int N)
{
  const int nblk = blockIdx.x;
  const int ks   = blockIdx.y;
  const int Kc   = K / NSPLIT;
  const int kbeg = ks * Kc;
  const int KT   = Kc / 32;
  const int tid  = threadIdx.x;
  const int w = tid >> 6, l = tid & 63;
  const int lane16 = l & 15, quad = l >> 4;
  const int m_base = w * 32;
  const int n_base = nblk * 64;

  __shared__ short Bs[2][32 * 64];

  // staging mapping: round r in {0,1}: k = r*16 + (tid>>4), n0 = (tid&15)*4
  const int ksl = tid >> 4;
  const int n0s = (tid & 15) * 4;
  int wsl[4];
  #pragma unroll
  for (int i = 0; i < 4; i++) wsl[i] = bslot(n0s + i) * 8;
  const int kb0 = ((ksl >> 3) << 9) | (ksl & 7);
  const int kb1 = (((ksl + 16) >> 3) << 9) | (ksl & 7);
  int rdoff[4];
  #pragma unroll
  for (int nt = 0; nt < 4; nt++) rdoff[nt] = quad * 512 + bslot(nt * 16 + lane16) * 8;

  f4 acc[2][4];
  #pragma unroll
  for (int i = 0; i < 2; i++)
    #pragma unroll
    for (int j = 0; j < 4; j++) { f4 z = {0.f,0.f,0.f,0.f}; acc[i][j] = z; }

  const float* Bp = B + (size_t)kbeg * N + n_base + n0s;
  const short* Ap = A + (size_t)(m_base + lane16) * K + kbeg + quad * 8;

  f4  r0a, r0b, r1a, r1b, r2a, r2b;
  s8v ac0, ac1, an0, an1;

  auto LDT = [&](int kt, f4& X, f4& Y) {
    const float* p = Bp + (size_t)(kt * 32 + ksl) * N;
    X = *(const f4*)p;
    Y = *(const f4*)(p + (size_t)16 * N);
  };
  auto LDAT = [&](int kt, s8v& X0, s8v& X1) {
    const short* q = Ap + kt * 32;
    X0 = *(const s8v*)q;
    X1 = *(const s8v*)(q + (size_t)16 * K);
  };

  LDT(0, r0a, r0b);
  if (KT > 1) LDT(1, r1a, r1b);
  LDAT(0, ac0, ac1);

  for (int kt = 0; kt < KT; kt++) {
    if (kt + 2 < KT) LDT(kt + 2, r2a, r2b);
    if (kt + 1 < KT) LDAT(kt + 1, an0, an1);
    {
      short* bs = &Bs[kt & 1][0];
      #pragma unroll
      for (int i = 0; i < 4; i++) {
        bs[kb0 + wsl[i]] = f2bf(r0a[i]);
        bs[kb1 + wsl[i]] = f2bf(r0b[i]);
      }
    }
    __syncthreads();
    {
      const short* bs = &Bs[kt & 1][0];
      s8v b[4];
      #pragma unroll
      for (int nt = 0; nt < 4; nt++) b[nt] = *(const s8v*)(bs + rdoff[nt]);
      #pragma unroll
      for (int nt = 0; nt < 4; nt++) {
        acc[0][nt] = __builtin_amdgcn_mfma_f32_16x16x32_bf16(ac0, b[nt], acc[0][nt], 0, 0, 0);
        acc[1][nt] = __builtin_amdgcn_mfma_f32_16x16x32_bf16(ac1, b[nt], acc[1][nt], 0, 0, 0);
      }
    }
    r0a = r1a; r0b = r1b; r1a = r2a; r1b = r2b;
    ac0 = an0; ac1 = an1;
  }

  if constexpr (OUT_BF16) {
    short* out = (short*)outv + (size_t)ks * 128 * N;
    #pragma unroll
    for (int mt = 0; mt < 2; mt++)
      #pragma unroll
      for (int nt = 0; nt < 4; nt++)
        #pragma unroll
        for (int r = 0; r < 4; r++)
          out[(size_t)(m_base + mt*16 + quad*4 + r) * N + n_base + nt*16 + lane16] =
              f2bf(acc[mt][nt][r]);
  } else {
    float* out = (float*)outv + (size_t)ks * 128 * N;
    #pragma unroll
    for (int mt = 0; mt < 2; mt++)
      #pragma unroll
      for (int nt = 0; nt < 4; nt++)
        #pragma unroll
        for (int r = 0; r < 4; r++)
          out[(size_t)(m_base + mt*16 + quad*4 + r) * N + n_base + nt*16 + lane16] =
              acc[mt][nt][r];
  }
}

// ---------------------------------------------------------------------------
// Fused gate/up GEMM + tanh-GELU * up epilogue -> ff bf16 [128][6912]
// BN=32, wave: mg=w&1 (64 rows), ng=w>>1 (16 cols), both weight matrices.
// Same LDS staging scheme, slice stride 256 elems (BN=32).
// ---------------------------------------------------------------------------
__global__ __launch_bounds__(256, 2) void gemm_gateup(
    const short* __restrict__ A, const float* __restrict__ Bg,
    const float* __restrict__ Bu, short* __restrict__ ff)
{
  const int nblk = blockIdx.x;
  const int tid  = threadIdx.x;
  const int w = tid >> 6, l = tid & 63;
  const int lane16 = l & 15, quad = l >> 4;
  const int mg = w & 1, ng = w >> 1;
  const int m_base = mg * 64;
  const int n_base = nblk * 32;
  const int n_col  = n_base + ng * 16 + lane16;

  __shared__ short Bsh[2][2][32 * 32];   // [buf][gate/up][elems]

  // staging: k = tid>>3 (0..31), n0 = (tid&7)*4
  const int kst = tid >> 3;
  const int n0s = (tid & 7) * 4;
  int wsl[4];
  #pragma unroll
  for (int i = 0; i < 4; i++) wsl[i] = bslot(n0s + i) * 8;
  const int kb  = ((kst >> 3) << 8) | (kst & 7);
  const int rdo = quad * 256 + bslot(ng * 16 + lane16) * 8;

  f4 accg[4], accu[4];
  #pragma unroll
  for (int i = 0; i < 4; i++) { f4 z = {0.f,0.f,0.f,0.f}; accg[i] = z; accu[i] = z; }

  const float* Bgp = Bg + (size_t)kst * Fm + n_base + n0s;
  const float* Bup = Bu + (size_t)kst * Fm + n_base + n0s;
  const short* Ap  = A + (size_t)(m_base + lane16) * Dm + quad * 8;

  f4 g0, u0, g1, u1, g2, u2;

  auto LDT = [&](int kt, f4& G, f4& U) {
    const size_t off = (size_t)(kt * 32) * Fm;
    G = *(const f4*)(Bgp + off);
    U = *(const f4*)(Bup + off);
  };

  LDT(0, g0, u0);
  LDT(1, g1, u1);

  for (int kt = 0; kt < 36; kt++) {
    if (kt + 2 < 36) LDT(kt + 2, g2, u2);
    {
      short* b0 = &Bsh[kt & 1][0][0];
      short* b1 = &Bsh[kt & 1][1][0];
      #pragma unroll
      for (int i = 0; i < 4; i++) {
        b0[kb + wsl[i]] = f2bf(g0[i]);
        b1[kb + wsl[i]] = f2bf(u0[i]);
      }
    }
    __syncthreads();
    {
      s8v a[4];
      const short* ap = Ap + kt * 32;
      #pragma unroll
      for (int mt = 0; mt < 4; mt++)
        a[mt] = *(const s8v*)(ap + (size_t)(mt * 16) * Dm);
      s8v bg = *(const s8v*)(&Bsh[kt & 1][0][rdo]);
      s8v bu = *(const s8v*)(&Bsh[kt & 1][1][rdo]);
      #pragma unroll
      for (int mt = 0; mt < 4; mt++) {
        accg[mt] = __builtin_amdgcn_mfma_f32_16x16x32_bf16(a[mt], bg, accg[mt], 0, 0, 0);
        accu[mt] = __builtin_amdgcn_mfma_f32_16x16x32_bf16(a[mt], bu, accu[mt], 0, 0, 0);
      }
    }
    g0 = g1; u0 = u1; g1 = g2; u1 = u2;
  }
  #pragma unroll
  for (int mt = 0; mt < 4; mt++)
    #pragma unroll
    for (int r = 0; r < 4; r++) {
      int rowi = m_base + mt*16 + quad*4 + r;
      float g = accg[mt][r], u = accu[mt][r];
      float y = 0.7978845608f * (g + 0.044715f * g * g * g);
      float sg = 1.f / (1.f + exp2f(y * -2.885390082f));   // sigmoid(2y)
      ff[(size_t)rowi * Fm + n_col] = f2bf(g * sg * u);
    }
}

// ---------------------------------------------------------------------------
// qkv epilogue: sum 6 bf16 split-K slices, per-head q RMS+RoPE -> qa bf16,
// k RMS+RoPE -> d_out k-slice (fp32), v -> d_out v-slice transposed.
// One block per token t.
// ---------------------------------------------------------------------------
__global__ __launch_bounds__(256) void qkv_prep(
    const short* __restrict__ qkv_part,   // [6][128][1536]
    const float* __restrict__ qnw, const float* __restrict__ knw,
    const float* __restrict__ cosb, const float* __restrict__ sinb, // [128][256]
    short* __restrict__ qa,               // [4][128][256]
    float* __restrict__ kout,             // [128][256] (d_out)
    float* __restrict__ vout)             // [256][128] (d_out)
{
  const int t = blockIdx.x;
  const int tid = threadIdx.x;
  __shared__ float row[1536];
  __shared__ float invs[5];
  for (int j = tid; j < 1536; j += 256) {
    float s = 0.f;
    #pragma unroll
    for (int c = 0; c < 6; c++)
      s += bf2f(qkv_part[(size_t)c * 128 * 1536 + (size_t)t * 1536 + j]);
    row[j] = s;
  }
  __syncthreads();
  const int w = tid >> 6, l = tid & 63;
  {
    float ps = 0.f;
    #pragma unroll
    for (int jj = 0; jj < 4; jj++) { float x = row[w*256 + jj*64 + l]; ps += x * x; }
    #pragma unroll
    for (int d = 1; d < 64; d <<= 1) ps += __shfl_xor(ps, d);
    if (l == 0) invs[w] = rsqrtf(ps * (1.f/256.f) + 1e-6f);
    if (w == 0) {
      float pk = 0.f;
      #pragma unroll
      for (int jj = 0; jj < 4; jj++) { float x = row[1024 + jj*64 + l]; pk += x * x; }
      #pragma unroll
      for (int d = 1; d < 64; d <<= 1) pk += __shfl_xor(pk, d);
      if (l == 0) invs[4] = rsqrtf(pk * (1.f/256.f) + 1e-6f);
    }
  }
  __syncthreads();
  {
    float inv = invs[w];
    #pragma unroll
    for (int jj = 0; jj < 2; jj++) {
      int d = jj*64 + l;                       // 0..127
      float x1 = row[w*256 + d]       * inv * (1.f + qnw[d]);
      float x2 = row[w*256 + d + 128] * inv * (1.f + qnw[d + 128]);
      float c1 = cosb[t*256 + d],       s1 = sinb[t*256 + d];
      float c2 = cosb[t*256 + d + 128], s2 = sinb[t*256 + d + 128];
      qa[(size_t)(w*128 + t)*256 + d]       = f2bf(x1 * c1 - x2 * s1);
      qa[(size_t)(w*128 + t)*256 + d + 128] = f2bf(x2 * c2 + x1 * s2);
    }
  }
  if (w == 1) {
    float inv = invs[4];
    #pragma unroll
    for (int jj = 0; jj < 2; jj++) {
      int d = jj*64 + l;
      float x1 = row[1024 + d]       * inv * (1.f + knw[d]);
      float x2 = row[1024 + d + 128] * inv * (1.f + knw[d + 128]);
      float c1 = cosb[t*256 + d],       s1 = sinb[t*256 + d];
      float c2 = cosb[t*256 + d + 128], s2 = sinb[t*256 + d + 128];
      kout[t*256 + d]       = x1 * c1 - x2 * s1;
      kout[t*256 + d + 128] = x2 * c2 + x1 * s2;
    }
  }
  if (w >= 2) {
    #pragma unroll
    for (int jj = 0; jj < 2; jj++) {
      int d = (w - 2)*128 + jj*64 + l;
      vout[(size_t)d * 128 + t] = row[1280 + d];
    }
  }
}

// ---------------------------------------------------------------------------
// Flash attention partial: block = (chunk 0..7, qtile 0..1, head 0..3).
// Scores 64x256 via MFMA, softcap tanh + analytic mask, online m/l,
// P->LDS(bf16)->PV MFMA. Writes m,l (fp32) and O (bf16) partials.
// Local layers: fully-out-of-window chunks early-exit (l=0, m=-1e30).
// ---------------------------------------------------------------------------
__global__ __launch_bounds__(256) void flash_partial(
    const short* __restrict__ qa,
    const float* __restrict__ kcache, const float* __restrict__ knew,
    const float* __restrict__ vcache, const float* __restrict__ vnew,
    float* __restrict__ m_part, float* __restrict__ l_part,
    short* __restrict__ o_part, int is_local)
{
  const int chunk = blockIdx.x, qt = blockIdx.y, h = blockIdx.z;
  const int tid = threadIdx.x;
  const int w = tid >> 6, l = tid & 63;
  const int lane16 = l & 15, quad = l >> 4;
  const int n0w = w * 64;
  const int t_base = qt * 64;
  const int s_base = chunk * 256;

  // fully window-masked chunk on local layers: keys all <= qpos_min - 1024
  if (is_local && (s_base + 255 < t_base + Cm - 1023)) {
    if (tid < 64) {
      int base = ((h*2 + qt)*8 + chunk) * 64;
      m_part[base + tid] = -1.0e30f;
      l_part[base + tid] = 0.f;
    }
    return;
  }

  __shared__ __align__(16) short P[64 * 264];
  __shared__ float red[256];

  f4 acc[4][4];
  #pragma unroll
  for (int i = 0; i < 4; i++)
    #pragma unroll
    for (int j = 0; j < 4; j++) { f4 z = {0.f,0.f,0.f,0.f}; acc[i][j] = z; }

  // ---- QK^T ----
  for (int kk = 0; kk < 8; kk++) {
    int k0 = kk * 32;
    s8v a[4];
    #pragma unroll
    for (int mt = 0; mt < 4; mt++)
      a[mt] = *(const s8v*)(qa + (size_t)(h*128 + t_base + mt*16 + lane16)*256 + k0 + quad*8);
    s8v b[4];
    #pragma unroll
    for (int nt = 0; nt < 4; nt++) {
      int sg = s_base + n0w + nt*16 + lane16;
      const float* kp = (sg < Cm) ? (kcache + (size_t)sg * 256)
                                  : (knew + (size_t)(sg - Cm) * 256);
      f4 f0 = *(const f4*)(kp + k0 + quad*8);
      f4 f1 = *(const f4*)(kp + k0 + quad*8 + 4);
      s8v t;
      #pragma unroll
      for (int j = 0; j < 4; j++) { t[j] = f2bf(f0[j]); t[4+j] = f2bf(f1[j]); }
      b[nt] = t;
    }
    #pragma unroll
    for (int mt = 0; mt < 4; mt++)
      #pragma unroll
      for (int nt = 0; nt < 4; nt++)
        acc[mt][nt] = __builtin_amdgcn_mfma_f32_16x16x32_bf16(a[mt], b[nt], acc[mt][nt], 0, 0, 0);
  }

  // ---- softcap + mask + row max ----
  int srel[4];
  #pragma unroll
  for (int nt = 0; nt < 4; nt++) srel[nt] = s_base + n0w + nt*16 + lane16 - Cm;
  float mrow[4][4];
  #pragma unroll
  for (int mt = 0; mt < 4; mt++)
    #pragma unroll
    for (int r = 0; r < 4; r++) {
      int trow = t_base + mt*16 + quad*4 + r;
      float mx = -3.4e38f;
      #pragma unroll
      for (int nt = 0; nt < 4; nt++) {
        float sc = acc[mt][nt][r];
        float e = exp2f(sc * K_TANH);
        float capped = 50.f - 100.f / (e + 1.f);
        bool ok = (srel[nt] <= trow) && (!is_local || (srel[nt] > trow - 1024));
        float vv = ok ? capped : (capped - 1e9f);
        acc[mt][nt][r] = vv;
        mx = fmaxf(mx, vv);
      }
      mrow[mt][r] = mx;
    }
  #pragma unroll
  for (int mt = 0; mt < 4; mt++)
    #pragma unroll
    for (int r = 0; r < 4; r++) {
      float m = mrow[mt][r];
      m = fmaxf(m, __shfl_xor(m, 1)); m = fmaxf(m, __shfl_xor(m, 2));
      m = fmaxf(m, __shfl_xor(m, 4)); m = fmaxf(m, __shfl_xor(m, 8));
      mrow[mt][r] = m;
    }
  if (lane16 == 0)
    #pragma unroll
    for (int mt = 0; mt < 4; mt++)
      #pragma unroll
      for (int r = 0; r < 4; r++) red[w*64 + mt*16 + quad*4 + r] = mrow[mt][r];
  __syncthreads();
  #pragma unroll
  for (int mt = 0; mt < 4; mt++)
    #pragma unroll
    for (int r = 0; r < 4; r++) {
      int rr = mt*16 + quad*4 + r;
      mrow[mt][r] = fmaxf(fmaxf(red[rr], red[64 + rr]), fmaxf(red[128 + rr], red[192 + rr]));
    }
  // ---- exp + row sum ----
  float lrow[4][4];
  #pragma unroll
  for (int mt = 0; mt < 4; mt++)
    #pragma unroll
    for (int r = 0; r < 4; r++) {
      float s = 0.f;
      #pragma unroll
      for (int nt = 0; nt < 4; nt++) {
        float p = exp2f((acc[mt][nt][r] - mrow[mt][r]) * LOG2E);
        acc[mt][nt][r] = p;
        s += p;
      }
      s += __shfl_xor(s, 1); s += __shfl_xor(s, 2);
      s += __shfl_xor(s, 4); s += __shfl_xor(s, 8);
      lrow[mt][r] = s;
    }
  __syncthreads();
  if (lane16 == 0)
    #pragma unroll
    for (int mt = 0; mt < 4; mt++)
      #pragma unroll
      for (int r = 0; r < 4; r++) red[w*64 + mt*16 + quad*4 + r] = lrow[mt][r];
  __syncthreads();
  if (w == 0 && lane16 == 0) {
    int base = ((h*2 + qt)*8 + chunk) * 64;
    #pragma unroll
    for (int mt = 0; mt < 4; mt++)
      #pragma unroll
      for (int r = 0; r < 4; r++) {
        int rr = mt*16 + quad*4 + r;
        m_part[base + rr] = mrow[mt][r];
        l_part[base + rr] = red[rr] + red[64 + rr] + red[128 + rr] + red[192 + rr];
      }
  }
  // ---- P -> LDS bf16 ----
  #pragma unroll
  for (int mt = 0; mt < 4; mt++)
    #pragma unroll
    for (int nt = 0; nt < 4; nt++)
      #pragma unroll
      for (int r = 0; r < 4; r++)
        P[(mt*16 + quad*4 + r)*264 + n0w + nt*16 + lane16] = f2bf(acc[mt][nt][r]);
  __syncthreads();

  // ---- P @ V ----
  f4 oacc[4][4];
  #pragma unroll
  for (int i = 0; i < 4; i++)
    #pragma unroll
    for (int j = 0; j < 4; j++) { f4 z = {0.f,0.f,0.f,0.f}; oacc[i][j] = z; }
  for (int kk = 0; kk < 8; kk++) {
    int k0 = kk * 32;
    s8v a[4];
    #pragma unroll
    for (int mt = 0; mt < 4; mt++)
      a[mt] = *(const s8v*)(&P[(mt*16 + lane16)*264 + k0 + quad*8]);
    s8v b[4];
    int s0 = s_base + k0 + quad*8;
    #pragma unroll
    for (int nt = 0; nt < 4; nt++) {
      int d = n0w + nt*16 + lane16;
      const float* vp = (s0 < Cm) ? (vcache + (size_t)d * Cm + s0)
                                  : (vnew + (size_t)d * 128 + (s0 - Cm));
      f4 f0 = *(const f4*)vp;
      f4 f1 = *(const f4*)(vp + 4);
      s8v t;
      #pragma unroll
      for (int j = 0; j < 4; j++) { t[j] = f2bf(f0[j]); t[4+j] = f2bf(f1[j]); }
      b[nt] = t;
    }
    #pragma unroll
    for (int mt = 0; mt < 4; mt++)
      #pragma unroll
      for (int nt = 0; nt < 4; nt++)
        oacc[mt][nt] = __builtin_amdgcn_mfma_f32_16x16x32_bf16(a[mt], b[nt], oacc[mt][nt], 0, 0, 0);
  }
  short* ob = o_part + (size_t)(((h*2 + qt)*8 + chunk) * 64) * 256;
  #pragma unroll
  for (int mt = 0; mt < 4; mt++)
    #pragma unroll
    for (int nt = 0; nt < 4; nt++)
      #pragma unroll
      for (int r = 0; r < 4; r++)
        ob[(size_t)(mt*16 + quad*4 + r)*256 + n0w + nt*16 + lane16] = f2bf(oacc[mt][nt][r]);
}

// ---------------------------------------------------------------------------
// Combine 8 chunk partials -> ao bf16 [128][1024] (= out.transpose reshaped)
// Skips chunks with we==0 (early-exited partials have uninitialized O).
// ---------------------------------------------------------------------------
__global__ __launch_bounds__(256) void attn_combine(
    const float* __restrict__ m_part, const float* __restrict__ l_part,
    const short* __restrict__ o_part, short* __restrict__ ao)
{
  const int qt = blockIdx.x, h = blockIdx.y;
  const int tid = threadIdx.x;
  const int row = tid >> 2, di = tid & 3;
  const int base = ((h*2 + qt)*8) * 64;
  float mc[8], we[8];
  float M = -3.4e38f;
  #pragma unroll
  for (int c = 0; c < 8; c++) { mc[c] = m_part[base + c*64 + row]; M = fmaxf(M, mc[c]); }
  float den = 0.f;
  #pragma unroll
  for (int c = 0; c < 8; c++) {
    we[c] = (mc[c] > -1e29f) ? exp2f((mc[c] - M) * LOG2E) : 0.f;
    den += we[c] * l_part[base + c*64 + row];
  }
  float invd = 1.f / den;
  const short* ob = o_part + (size_t)base * 256;
  for (int i = 0; i < 64; i++) {
    int d = di + i*4;
    float o = 0.f;
    #pragma unroll
    for (int c = 0; c < 8; c++)
      if (we[c] > 0.f)
        o += we[c] * bf2f(ob[(size_t)(c*64 + row)*256 + d]);
    ao[(size_t)(qt*64 + row)*1024 + h*256 + d] = f2bf(o * invd);
  }
}

// ---------------------------------------------------------------------------
// Residual epilogue: sum NS bf16 split-K slices -> p; h += rms(p,w1);
// xb = bf16(rms(h,w2)). One block per token.
// ---------------------------------------------------------------------------
__device__ inline float block_sum256(float v, float* red4) {
  #pragma unroll
  for (int d = 1; d < 64; d <<= 1) v += __shfl_xor(v, d);
  int w = threadIdx.x >> 6;
  if ((threadIdx.x & 63) == 0) red4[w] = v;
  __syncthreads();
  float s = red4[0] + red4[1] + red4[2] + red4[3];
  __syncthreads();
  return s;
}

template<int NS>
__global__ __launch_bounds__(256) void resid_norm(
    const short* __restrict__ part, const float* __restrict__ w1,
    float* __restrict__ h, const float* __restrict__ w2, short* __restrict__ xb)
{
  const int t = blockIdx.x, tid = threadIdx.x;
  __shared__ float red4[4];
  float pv[5]; float ssq = 0.f;
  #pragma unroll
  for (int k = 0; k < 5; k++) {
    int j = tid + k*256; pv[k] = 0.f;
    if (j < Dm) {
      float s = 0.f;
      #pragma unroll
      for (int c = 0; c < NS; c++)
        s += bf2f(part[(size_t)c * 128 * Dm + (size_t)t * Dm + j]);
      pv[k] = s; ssq += s * s;
    }
  }
  float tot = block_sum256(ssq, red4);
  float inv = rsqrtf(tot * (1.f / Dm) + 1e-6f);
  float hv[5]; float ssq2 = 0.f;
  #pragma unroll
  for (int k = 0; k < 5; k++) {
    int j = tid + k*256; hv[k] = 0.f;
    if (j < Dm) {
      float hn = h[(size_t)t * Dm + j] + pv[k] * inv * (1.f + w1[j]);
      h[(size_t)t * Dm + j] = hn;
      hv[k] = hn; ssq2 += hn * hn;
    }
  }
  float tot2 = block_sum256(ssq2, red4);
  float inv2 = rsqrtf(tot2 * (1.f / Dm) + 1e-6f);
  #pragma unroll
  for (int k = 0; k < 5; k++) {
    int j = tid + k*256;
    if (j < Dm) xb[(size_t)t * Dm + j] = f2bf(hv[k] * inv2 * (1.f + w2[j]));
  }
}

__global__ __launch_bounds__(256) void init_h(
    const float* __restrict__ emb, const float* __restrict__ w0,
    float* __restrict__ h, short* __restrict__ xb)
{
  const int t = blockIdx.x, tid = threadIdx.x;
  __shared__ float red4[4];
  float pv[5]; float ssq = 0.f;
  #pragma unroll
  for (int k = 0; k < 5; k++) {
    int j = tid + k*256; pv[k] = 0.f;
    if (j < Dm) { float v = emb[(size_t)t * Dm + j]; h[(size_t)t * Dm + j] = v; pv[k] = v; ssq += v * v; }
  }
  float tot = block_sum256(ssq, red4);
  float inv = rsqrtf(tot * (1.f / Dm) + 1e-6f);
  #pragma unroll
  for (int k = 0; k < 5; k++) {
    int j = tid + k*256;
    if (j < Dm) xb[(size_t)t * Dm + j] = f2bf(pv[k] * inv * (1.f + w0[j]));
  }
}

// ---------------------------------------------------------------------------
extern "C" void kernel_launch(void* const* d_in, const int* in_sizes, int n_in,
                              void* d_out, int out_size, void* d_ws, size_t ws_size,
                              hipStream_t stream) {
  const float* emb      = (const float*)d_in[0];
  const float* pe_cos   = (const float*)d_in[3];
  const float* pe_sin   = (const float*)d_in[4];
  const float* pe_cosl  = (const float*)d_in[5];
  const float* pe_sinl  = (const float*)d_in[6];
  const float* kv_k     = (const float*)d_in[7];
  const float* kv_v     = (const float*)d_in[8];
  const float* pre_attn = (const float*)d_in[9];
  const float* q_norm   = (const float*)d_in[10];
  const float* k_norm   = (const float*)d_in[11];
  const float* post_attn= (const float*)d_in[12];
  const float* pre_ff   = (const float*)d_in[13];
  const float* post_ff  = (const float*)d_in[14];
  const float* final_w  = (const float*)d_in[15];
  const float* w_qkv    = (const float*)d_in[16];
  const float* w_out    = (const float*)d_in[17];
  const float* w_gate   = (const float*)d_in[18];
  const float* w_up     = (const float*)d_in[19];
  const float* w_down   = (const float*)d_in[20];
  const float* w_lm     = (const float*)d_in[21];

  float* outp    = (float*)d_out;
  float* logits  = outp;                                  // [128][32768]
  float* k_out0  = outp + (size_t)Tm * Vv;                // [12][128][256]
  float* v_out0  = k_out0 + (size_t)12 * Tm * HD;         // [12][256][128]

  char* ws = (char*)d_ws;
  auto alloc = [&](size_t bytes) { char* p = ws; ws += (bytes + 255) & ~(size_t)255; return p; };
  float* h     = (float*)alloc((size_t)Tm * Dm * 4);
  short* xb    = (short*)alloc((size_t)Tm * Dm * 2);
  short* qkvp  = (short*)alloc((size_t)6 * Tm * 1536 * 2);
  short* qa    = (short*)alloc((size_t)4 * Tm * HD * 2);
  float* m_p   = (float*)alloc((size_t)4 * 2 * 8 * 64 * 4);
  float* l_p   = (float*)alloc((size_t)4 * 2 * 8 * 64 * 4);
  short* o_p   = (short*)alloc((size_t)4 * 2 * 8 * 64 * 256 * 2);
  short* ao    = (short*)alloc((size_t)Tm * 1024 * 2);
  short* projp = (short*)alloc((size_t)8 * Tm * Dm * 2);
  short* ffb   = (short*)alloc((size_t)Tm * Fm * 2);
  short* downp = (short*)alloc((size_t)12 * Tm * Dm * 2);

  init_h<<<128, 256, 0, stream>>>(emb, pre_attn, h, xb);

  for (int i = 0; i < 12; i++) {
    const int loc = ((i + 1) % 6 == 0) ? 1 : 0;
    const float* cb = loc ? pe_cosl : pe_cos;
    const float* sb = loc ? pe_sinl : pe_sin;
    float* kout = k_out0 + (size_t)i * Tm * HD;
    float* vout = v_out0 + (size_t)i * HD * Tm;

    gemm_bf16<6, true><<<dim3(24, 6), 256, 0, stream>>>(
        xb, w_qkv + (size_t)i * Dm * 1536, qkvp, Dm, 1536);
    qkv_prep<<<128, 256, 0, stream>>>(qkvp, q_norm + i * HD, k_norm + i * HD,
                                      cb, sb, qa, kout, vout);
    flash_partial<<<dim3(8, 2, 4), 256, 0, stream>>>(
        qa, kv_k + (size_t)i * Cm * HD, kout,
        kv_v + (size_t)i * HD * Cm, vout, m_p, l_p, o_p, loc);
    attn_combine<<<dim3(2, 4), 256, 0, stream>>>(m_p, l_p, o_p, ao);
    gemm_bf16<8, true><<<dim3(18, 8), 256, 0, stream>>>(
        ao, w_out + (size_t)i * 1024 * Dm, projp, 1024, Dm);
    resid_norm<8><<<128, 256, 0, stream>>>(projp, post_attn + i * Dm, h, pre_ff + i * Dm, xb);
    gemm_gateup<<<216, 256, 0, stream>>>(
        xb, w_gate + (size_t)i * Dm * Fm, w_up + (size_t)i * Dm * Fm, ffb);
    gemm_bf16<12, true><<<dim3(18, 12), 256, 0, stream>>>(
        ffb, w_down + (size_t)i * Fm * Dm, downp, Fm, Dm);
    const float* nw = (i < 11) ? (pre_attn + (i + 1) * Dm) : final_w;
    resid_norm<12><<<128, 256, 0, stream>>>(downp, post_ff + i * Dm, h, nw, xb);
  }

  gemm_bf16<1, false><<<dim3(512, 1), 256, 0, stream>>>(
      xb, w_lm, logits, Dm, Vv);
}